// Round 3
// baseline (120.514 us; speedup 1.0000x reference)
//
#include <hip/hip_runtime.h>

// PopulationLayer: lateral = pa @ (W with zeroed diag); v_new = exp(-0.1)*v + ext - lateral;
// out = (v_new > threshold) ? 1 : 0   (straight-through forward == hard)
//
// Output is BINARY -> absmax 0.02 means zero decision flips allowed.
// fp64 accumulation everywhere -> matches fp64 numpy ref to ~1e-13 (R1/R2: absmax 0.0).
//
// R3 changes: reduce widened 64->512 blocks (was 25%-of-chip BW-starved),
// nontemporal loads on the once-streamed W / ext / v / thr and nt store on out.

#define PP 4096
#define BB 256

using f4 = __attribute__((ext_vector_type(4))) float;

constexpr int ROWS_PER_CHUNK = 16;
constexpr int NCHUNK = PP / ROWS_PER_CHUNK;   // 256
constexpr int COLS_PER_TILE = 1024;
constexpr int NTILE = PP / COLS_PER_TILE;     // 4

// Stage 1: deterministic partial sums. grid = NTILE*NCHUNK = 1024 blocks, 256 thr.
// Each thread owns 4 adjacent columns (nt float4 load), 16 rows, fully unrolled.
__global__ __launch_bounds__(256)
void lateral_partial(const float* __restrict__ w, const float* __restrict__ pa,
                     double* __restrict__ part) {
    const int tile = blockIdx.x & (NTILE - 1);
    const int rch  = blockIdx.x >> 2;               // NTILE == 4
    const int c    = tile * COLS_PER_TILE + (int)threadIdx.x * 4;
    const int r0   = rch * ROWS_PER_CHUNK;
    double a0 = 0.0, a1 = 0.0, a2 = 0.0, a3 = 0.0;
#pragma unroll
    for (int k = 0; k < ROWS_PER_CHUNK; ++k) {
        const int i = r0 + k;
        const double p = (double)pa[i];             // block-uniform -> scalar load
        const f4 wv = __builtin_nontemporal_load(
            reinterpret_cast<const f4*>(w + (size_t)i * PP + c));
        a0 += p * (double)wv.x;
        a1 += p * (double)wv.y;
        a2 += p * (double)wv.z;
        a3 += p * (double)wv.w;
    }
    double* dst = part + (size_t)rch * PP + c;
    *reinterpret_cast<double2*>(dst)     = make_double2(a0, a1);
    *reinterpret_cast<double2*>(dst + 2) = make_double2(a2, a3);
}

// Stage 2: reduce NCHUNK partials per column, subtract diagonal term.
// grid = PP/8 = 512 blocks; 256 thr = 8 cols x 32 chunk-groups (8 chunks each).
// Lanes 0-7 read 64 contiguous bytes -> full-line coalesced.
__global__ __launch_bounds__(256)
void lateral_reduce(const double* __restrict__ part, const float* __restrict__ w,
                    const float* __restrict__ pa, double* __restrict__ lat) {
    __shared__ double sh[256];
    const int t   = (int)threadIdx.x;
    const int cj  = t & 7;                 // col within block
    const int grp = t >> 3;                // 32 chunk-groups
    const int col = blockIdx.x * 8 + cj;
    double s = 0.0;
#pragma unroll
    for (int k = 0; k < NCHUNK / 32; ++k)  // 8 chunks per group
        s += part[(size_t)(grp * 8 + k) * PP + col];
    sh[t] = s;
    __syncthreads();
#pragma unroll
    for (int off = 128; off >= 8; off >>= 1) {
        if (t < off) sh[t] += sh[t + off];
        __syncthreads();
    }
    if (t < 8) {
        // remove self-connection: the full sum included pa[col]*W[col,col]
        lat[col] = sh[t] - (double)pa[col] * (double)w[(size_t)col * (PP + 1)];
    }
}

// Stage 3: elementwise LIF + hard spike. grid = B*P/(4*256) = 1024 blocks.
__global__ __launch_bounds__(256)
void spike(const float* __restrict__ ext, const float* __restrict__ v,
           const float* __restrict__ thr, const double* __restrict__ lat,
           float* __restrict__ out) {
    const size_t t = ((size_t)blockIdx.x * 256 + threadIdx.x) * 4;
    const int j = (int)(t & (PP - 1));
    const f4 e  = __builtin_nontemporal_load(reinterpret_cast<const f4*>(ext + t));
    const f4 vv = __builtin_nontemporal_load(reinterpret_cast<const f4*>(v + t));
    const f4 th = __builtin_nontemporal_load(reinterpret_cast<const f4*>(thr + t));
    const double l0 = lat[j], l1 = lat[j + 1], l2 = lat[j + 2], l3 = lat[j + 3];
    const double dec = 0.90483741803595952;  // exp(-0.1) in fp64
    f4 o;
    o.x = (dec * (double)vv.x + (double)e.x - l0 > (double)th.x) ? 1.0f : 0.0f;
    o.y = (dec * (double)vv.y + (double)e.y - l1 > (double)th.y) ? 1.0f : 0.0f;
    o.z = (dec * (double)vv.z + (double)e.z - l2 > (double)th.z) ? 1.0f : 0.0f;
    o.w = (dec * (double)vv.w + (double)e.w - l3 > (double)th.w) ? 1.0f : 0.0f;
    __builtin_nontemporal_store(o, reinterpret_cast<f4*>(out + t));
}

extern "C" void kernel_launch(void* const* d_in, const int* in_sizes, int n_in,
                              void* d_out, int out_size, void* d_ws, size_t ws_size,
                              hipStream_t stream) {
    const float* ext = (const float*)d_in[0];   // [B,P]
    const float* w   = (const float*)d_in[1];   // [P,P]
    const float* pa  = (const float*)d_in[2];   // [P]
    const float* v   = (const float*)d_in[3];   // [B,P]
    const float* thr = (const float*)d_in[4];   // [B,P]
    float* out = (float*)d_out;

    double* part = (double*)d_ws;                       // NCHUNK*PP doubles = 8 MiB
    double* lat  = part + (size_t)NCHUNK * PP;          // PP doubles = 32 KiB

    lateral_partial<<<NTILE * NCHUNK, 256, 0, stream>>>(w, pa, part);
    lateral_reduce<<<PP / 8, 256, 0, stream>>>(part, w, pa, lat);
    spike<<<(BB * PP) / (4 * 256), 256, 0, stream>>>(ext, v, thr, lat, out);
}

// Round 4
// 111.682 us; speedup vs baseline: 1.0791x; 1.0791x over previous
//
#include <hip/hip_runtime.h>

// PopulationLayer: lateral = pa @ (W with zeroed diag); v_new = exp(-0.1)*v + ext - lateral;
// out = (v_new > threshold) ? 1 : 0   (straight-through forward == hard)
//
// Output is BINARY -> absmax 0.02 means zero decision flips allowed.
// fp64 accumulation everywhere -> matches fp64 numpy ref to ~1e-13 (R1-R3: absmax 0.0).
//
// R4: revert R3's nontemporal hints (unattributed regression), halve partial
// round-trip (NCHUNK 256->128 via 32-row chunks, 8-way column split w/ float2),
// reduce right-sized to 128 blocks w/ coalesced 256B reads, double2 lat loads.

#define PP 4096
#define BB 256

using f4 = __attribute__((ext_vector_type(4))) float;

constexpr int ROWS_PER_CHUNK = 32;
constexpr int NCHUNK = PP / ROWS_PER_CHUNK;   // 128
constexpr int COLS_PER_TILE = 512;
constexpr int NTILE = PP / COLS_PER_TILE;     // 8

// Stage 1: deterministic partial sums. grid = NTILE*NCHUNK = 1024 blocks, 256 thr.
// Each thread owns 2 adjacent columns (float2 load), 32 rows, fully unrolled.
__global__ __launch_bounds__(256)
void lateral_partial(const float* __restrict__ w, const float* __restrict__ pa,
                     double* __restrict__ part) {
    const int tile = blockIdx.x & (NTILE - 1);
    const int rch  = blockIdx.x >> 3;               // NTILE == 8
    const int c    = tile * COLS_PER_TILE + (int)threadIdx.x * 2;
    const int r0   = rch * ROWS_PER_CHUNK;
    double a0 = 0.0, a1 = 0.0;
#pragma unroll
    for (int k = 0; k < ROWS_PER_CHUNK; ++k) {
        const int i = r0 + k;
        const double p = (double)pa[i];             // block-uniform -> scalar load
        const float2 wv = *reinterpret_cast<const float2*>(w + (size_t)i * PP + c);
        a0 += p * (double)wv.x;
        a1 += p * (double)wv.y;
    }
    *reinterpret_cast<double2*>(part + (size_t)rch * PP + c) = make_double2(a0, a1);
}

// Stage 2: reduce NCHUNK partials per column, subtract diagonal term.
// grid = PP/32 = 128 blocks; 256 thr = 32 cols x 8 chunk-groups (16 chunks each).
// 32 consecutive lanes read 32 adjacent doubles -> 256B coalesced.
__global__ __launch_bounds__(256)
void lateral_reduce(const double* __restrict__ part, const float* __restrict__ w,
                    const float* __restrict__ pa, double* __restrict__ lat) {
    __shared__ double sh[256];
    const int t   = (int)threadIdx.x;
    const int cj  = t & 31;                // col within block
    const int grp = t >> 5;                // 8 chunk-groups
    const int col = blockIdx.x * 32 + cj;
    double s = 0.0;
#pragma unroll
    for (int k = 0; k < NCHUNK / 8; ++k)   // 16 chunks per group
        s += part[(size_t)(grp * (NCHUNK / 8) + k) * PP + col];
    sh[t] = s;
    __syncthreads();
    if (t < 128) sh[t] += sh[t + 128];
    __syncthreads();
    if (t < 64)  sh[t] += sh[t + 64];
    __syncthreads();
    if (t < 32) {
        double r = sh[t] + sh[t + 32];
        // remove self-connection: the full sum included pa[col]*W[col,col]
        lat[col] = r - (double)pa[col] * (double)w[(size_t)col * (PP + 1)];
    }
}

// Stage 3: elementwise LIF + hard spike. grid = B*P/(4*256) = 1024 blocks.
__global__ __launch_bounds__(256)
void spike(const float* __restrict__ ext, const float* __restrict__ v,
           const float* __restrict__ thr, const double* __restrict__ lat,
           float* __restrict__ out) {
    const size_t t = ((size_t)blockIdx.x * 256 + threadIdx.x) * 4;
    const int j = (int)(t & (PP - 1));
    const f4 e  = *reinterpret_cast<const f4*>(ext + t);
    const f4 vv = *reinterpret_cast<const f4*>(v + t);
    const f4 th = *reinterpret_cast<const f4*>(thr + t);
    const double2 lA = *reinterpret_cast<const double2*>(lat + j);
    const double2 lB = *reinterpret_cast<const double2*>(lat + j + 2);
    const double dec = 0.90483741803595952;  // exp(-0.1) in fp64
    f4 o;
    o.x = (dec * (double)vv.x + (double)e.x - lA.x > (double)th.x) ? 1.0f : 0.0f;
    o.y = (dec * (double)vv.y + (double)e.y - lA.y > (double)th.y) ? 1.0f : 0.0f;
    o.z = (dec * (double)vv.z + (double)e.z - lB.x > (double)th.z) ? 1.0f : 0.0f;
    o.w = (dec * (double)vv.w + (double)e.w - lB.y > (double)th.w) ? 1.0f : 0.0f;
    *reinterpret_cast<f4*>(out + t) = o;
}

extern "C" void kernel_launch(void* const* d_in, const int* in_sizes, int n_in,
                              void* d_out, int out_size, void* d_ws, size_t ws_size,
                              hipStream_t stream) {
    const float* ext = (const float*)d_in[0];   // [B,P]
    const float* w   = (const float*)d_in[1];   // [P,P]
    const float* pa  = (const float*)d_in[2];   // [P]
    const float* v   = (const float*)d_in[3];   // [B,P]
    const float* thr = (const float*)d_in[4];   // [B,P]
    float* out = (float*)d_out;

    double* part = (double*)d_ws;                       // NCHUNK*PP doubles = 4 MiB
    double* lat  = part + (size_t)NCHUNK * PP;          // PP doubles = 32 KiB

    lateral_partial<<<NTILE * NCHUNK, 256, 0, stream>>>(w, pa, part);
    lateral_reduce<<<PP / 32, 256, 0, stream>>>(part, w, pa, lat);
    spike<<<(BB * PP) / (4 * 256), 256, 0, stream>>>(ext, v, thr, lat, out);
}